// Round 7
// baseline (298.184 us; speedup 1.0000x reference)
//
#include <hip/hip_runtime.h>
#include <math.h>

#define N_TOK 131072
#define N_E   1024
#define E_DIM 64
#define BETA  0.4

// d_out layout (float32, concatenated in return order):
#define ZQ_OFF   0
#define LOSS_OFF 8388608
#define IDX_OFF  8388609
#define PERP_OFF 8519681

// d_ws layout (round-2 pass proves ws_size >= 532492; we use 339984):
#define WS_C2    0        // 1024 f32: RN32(exact ||c_e||^2)
#define WS_C2I   4096     // 1024 i32: round(c2 * 128/(s_z*s_c))
#define WS_CNT   8192     // 1024 i32 counts
#define WS_SSQ   12288    // double sum_sq
#define WS_WLC   12296    // int worklist count (+4 pad)
#define WS_FHI   12304    // 65536 B: codebook int8-hi, MFMA B-frag layout
#define WS_FLO   77840    // 65536 B: codebook int8-lo
#define WS_WL    143376   // 16384 ints: worklist
#define WS_KEYS  208912   // 16384 u64: packed (d_bits<<32)|e
#define WLCAP    16384

// fixed-point scales: z = s_z*(zh + zl/256), s_z = 8/127 (|z|<8 guaranteed,
// N(0,1) max ~5.8); c = s_c*(ch + cl/256), s_c = (1/1024)/127 (|c|<=1/1024).
#define INV_SZ  15.875f        // 127/8
#define INV_SC  130048.0f      // 127*1024
#define SCALE_D 264257536.0    // 128/(s_z*s_c): c2 -> int units
#define BIGC    0x20000000     // +2^29 offset keeps tracker value positive

typedef int i32x4 __attribute__((ext_vector_type(4)));
typedef unsigned long long u64;

__device__ __forceinline__ void gl2lds16(const void* g, void* l) {
    __builtin_amdgcn_global_load_lds(
        (const __attribute__((address_space(1))) unsigned int*)g,
        (__attribute__((address_space(3))) unsigned int*)l, 16, 0, 0);
}

// One prep kernel: int8 hi/lo B-fragments + c2/c2i + zero-inits.
// Frag element j (0..15) of lane l, chunk c: cb[c*16+(l&15)][(l>>4)*16+j]
// at byte (c*64+l)*16+j  -> wave loads lane*16B contiguous.
__global__ __launch_bounds__(256) void prep_kernel(
    const float* __restrict__ cb, float* __restrict__ c2,
    int* __restrict__ c2i, int* __restrict__ counts, int* __restrict__ wlc,
    double* __restrict__ sum_sq, char* __restrict__ fhi,
    char* __restrict__ flo, u64* __restrict__ keys) {
    int tid = blockIdx.x * 256 + threadIdx.x;   // 65536
    int j = tid & 15, l = (tid >> 4) & 63, c = tid >> 10;
    int code = c * 16 + (l & 15);
    int k = ((l >> 4) << 4) | j;
    float cv = cb[code * 64 + k];
    float f = cv * INV_SC;
    float h = rintf(f);
    float lo = rintf((f - h) * 256.f);
    lo = fminf(fmaxf(lo, -127.f), 127.f);
    fhi[tid] = (char)(int)h;
    flo[tid] = (char)(int)lo;
    if (tid < WLCAP) keys[tid] = ~0ull;
    if (tid < N_E) {
        const float* p = cb + tid * 64;
        double s = 0.0;
#pragma unroll
        for (int i = 0; i < 64; ++i) { double d = (double)p[i]; s = fma(d, d, s); }
        c2[tid] = (float)s;
        c2i[tid] = (int)llround(s * SCALE_D);
        counts[tid] = 0;
    }
    if (tid == 0) { *wlc = 0; *sum_sq = 0.0; }
}

// Cold path (worklist overflow only). Exact numpy-f32 semantics, serial.
__device__ __attribute__((noinline)) int exact_best_serial(
    const float* __restrict__ z, const float* __restrict__ cb,
    const float* __restrict__ c2, int n) {
    const float* zr = z + (size_t)n * E_DIM;
    float r[8];
#pragma unroll
    for (int j = 0; j < 8; ++j) r[j] = __fmul_rn(zr[j], zr[j]);
#pragma unroll 1
    for (int i = 8; i < 64; i += 8)
#pragma unroll
        for (int j = 0; j < 8; ++j)
            r[j] = __fadd_rn(r[j], __fmul_rn(zr[i + j], zr[i + j]));
    float z2 = __fadd_rn(__fadd_rn(__fadd_rn(r[0], r[1]), __fadd_rn(r[2], r[3])),
                         __fadd_rn(__fadd_rn(r[4], r[5]), __fadd_rn(r[6], r[7])));
    u64 bestkey = ~0ull;
#pragma unroll 1
    for (int e = 0; e < N_E; ++e) {
        const float* cp = cb + (size_t)e * E_DIM;
        double m = 0.0;
#pragma unroll 1
        for (int i = 0; i < E_DIM; ++i)
            m = fma((double)zr[i], (double)cp[i], m);
        float d = __fsub_rn(__fadd_rn(z2, c2[e]), __fmul_rn(2.0f, (float)m));
        u64 key = ((u64)__float_as_uint(d) << 32) | (unsigned)e;
        if (key < bestkey) bestkey = key;
    }
    return (int)(bestkey & 0xffffffffu);
}

// Screen: 1024 blocks x 128 tokens, 4 blocks/CU, r5 double-barrier K-loop.
// i8 MFMA: v = 256*(zh.ch) + (zh.cl + zl.ch) + 2^29 - c2_int; max-tracker
// on packed key (v & ~63)|(63-c); dropped ll-term and chop covered by margin.
__global__ __launch_bounds__(256, 4) void vq_main(
    const float* __restrict__ z, const float* __restrict__ cb,
    const float* __restrict__ c2, const int* __restrict__ c2i,
    const char* __restrict__ fhi_, const char* __restrict__ flo_,
    int* __restrict__ counts, double* __restrict__ sum_sq,
    int* __restrict__ wl_count, int* __restrict__ wl,
    unsigned margin_v, float* __restrict__ out) {

    __shared__ char stagebuf[2][8192];   // [hi 4K | lo 4K] per buffer
    __shared__ int  c2i_s[N_E];
    __shared__ int  best_s[128];
    __shared__ unsigned char flag_s[128];
    __shared__ double wred[4];

    const int tid  = threadIdx.x;
    const int lane = tid & 63;
    const int wid  = tid >> 6;
    const int col  = lane & 15;
    const int quad = lane >> 4;
    const int blk_tok0 = blockIdx.x * 128;
    const int wave_tok0 = blk_tok0 + wid * 32;

#pragma unroll
    for (int i = 0; i < 4; ++i) c2i_s[tid * 4 + i] = c2i[tid * 4 + i];

    // ---- A fragments: 2 tiles, int8 hi/lo, K=64 in one frag ----
    i32x4 Ah[2], Al[2];
#pragma unroll
    for (int m = 0; m < 2; ++m) {
        const float* zr = z + (size_t)(wave_tok0 + m * 16 + col) * E_DIM + quad * 16;
        float e[16];
#pragma unroll
        for (int t = 0; t < 4; ++t) {
            float4 v = *(const float4*)(zr + t * 4);
            e[4 * t] = v.x; e[4 * t + 1] = v.y; e[4 * t + 2] = v.z; e[4 * t + 3] = v.w;
        }
        union { char b[16]; i32x4 v; } ph, pl;
#pragma unroll
        for (int t = 0; t < 16; ++t) {
            float f = e[t] * INV_SZ;           // |f| <= 127 (|z| < 8)
            float h = rintf(f);
            float lo = rintf((f - h) * 256.f);
            lo = fminf(fmaxf(lo, -127.f), 127.f);
            ph.b[t] = (char)(int)h;
            pl.b[t] = (char)(int)lo;
        }
        Ah[m] = ph.v;
        Al[m] = pl.v;
    }

    unsigned k1[2][4], k2[2][4];
#pragma unroll
    for (int m = 0; m < 2; ++m)
#pragma unroll
        for (int r = 0; r < 4; ++r) { k1[m][r] = 0u; k2[m][r] = 0u; }

    auto stage = [&](int s, int b) {
        gl2lds16(fhi_ + s * 4096 + tid * 16, &stagebuf[b][tid * 16]);
        gl2lds16(flo_ + s * 4096 + tid * 16, &stagebuf[b][4096 + tid * 16]);
    };

    const i32x4 zeroi = {0, 0, 0, 0};
    stage(0, 0);
    for (int s = 0; s < 16; ++s) {
        __syncthreads();              // staged data for s ready (vmcnt drained)
        if (s + 1 < 16) stage(s + 1, (s + 1) & 1);
        const char* hb = &stagebuf[s & 1][0];
        const char* lb = &stagebuf[s & 1][4096];
#pragma unroll
        for (int cl = 0; cl < 4; ++cl) {
            const int c = s * 4 + cl;
            i32x4 bh = *(const i32x4*)(hb + cl * 1024 + lane * 16);
            i32x4 bl = *(const i32x4*)(lb + cl * 1024 + lane * 16);
            int bias = BIGC - c2i_s[c * 16 + col];
            i32x4 cinit = {bias, bias, bias, bias};
            const unsigned ctag = (unsigned)(63 - c);
#pragma unroll
            for (int m = 0; m < 2; ++m) {
                i32x4 ahh = __builtin_amdgcn_mfma_i32_16x16x64_i8(Ah[m], bh, zeroi, 0, 0, 0);
                i32x4 amd = __builtin_amdgcn_mfma_i32_16x16x64_i8(Ah[m], bl, cinit, 0, 0, 0);
                amd = __builtin_amdgcn_mfma_i32_16x16x64_i8(Al[m], bh, amd, 0, 0, 0);
#pragma unroll
                for (int r = 0; r < 4; ++r) {
                    unsigned v = ((unsigned)ahh[r] << 8) + (unsigned)amd[r];
                    unsigned key = (v & 0xFFFFFFC0u) | ctag;
                    unsigned lo2 = min(k1[m][r], key);
                    k2[m][r] = max(k2[m][r], lo2);
                    k1[m][r] = max(k1[m][r], key);
                }
            }
        }
        __syncthreads();
    }

    // merge + decide, per (m,r): maximize key; ties -> higher ctag (lower
    // chunk) via key order, then lower col explicitly.
#pragma unroll
    for (int m = 0; m < 2; ++m) {
#pragma unroll
        for (int r = 0; r < 4; ++r) {
            unsigned ku1 = k1[m][r], ku2 = k2[m][r];
            int b1 = (63 - (int)(ku1 & 63u)) * 16 + col;
#pragma unroll
            for (int d = 1; d < 16; d <<= 1) {
                unsigned o1 = (unsigned)__shfl_xor((int)ku1, d, 64);
                unsigned o2 = (unsigned)__shfl_xor((int)ku2, d, 64);
                int      ob = __shfl_xor(b1, d, 64);
                unsigned n2 = max(max(ku2, o2), min(ku1, o1));
                bool take = (o1 > ku1) || (o1 == ku1 && ob < b1);
                ku1 = max(ku1, o1);
                b1 = take ? ob : b1;
                ku2 = n2;
            }
            if (col == 0) {
                int tl = wid * 32 + m * 16 + quad * 4 + r;
                int n  = blk_tok0 + tl;
                int best = b1;
                bool fl = (ku1 - ku2) < margin_v;   // ku1 >= ku2 always
                if (fl) {
                    int pos = atomicAdd(wl_count, 1);
                    if (pos < WLCAP) wl[pos] = n;
                    else { best = exact_best_serial(z, cb, c2, n); fl = false; }
                }
                best_s[tl] = best;
                flag_s[tl] = fl ? 1 : 0;
                if (!fl) atomicAdd(&counts[best], 1);
            }
        }
    }
    __syncthreads();

    // coalesced idx write (flagged slots overwritten by fixup_apply)
    if (tid < 128) out[IDX_OFF + blk_tok0 + tid] = (float)best_s[tid];

    // epilogue: coalesced z_q / loss for unflagged tokens
    const int sub = tid & 15, grp = tid >> 4;
    double dl = 0.0;
    const float4* zrow = (const float4*)z;
    const float4* crow = (const float4*)cb;
    float4* qrow = (float4*)(out + ZQ_OFF);
#pragma unroll
    for (int p = 0; p < 8; ++p) {
        int tl = p * 16 + grp;
        if (!flag_s[tl]) {
            int n = blk_tok0 + tl;
            float4 z4 = zrow[(size_t)n * 16 + sub];
            float4 c4 = crow[(size_t)best_s[tl] * 16 + sub];
            float dx = c4.x - z4.x, dy = c4.y - z4.y;
            float dz = c4.z - z4.z, dw = c4.w - z4.w;
            float4 q;
            q.x = z4.x + dx; q.y = z4.y + dy;
            q.z = z4.z + dz; q.w = z4.w + dw;
            qrow[(size_t)n * 16 + sub] = q;
            dl += (double)dx * dx + (double)dy * dy
                + (double)dz * dz + (double)dw * dw;
        }
    }
#pragma unroll
    for (int off = 32; off > 0; off >>= 1)
        dl += __shfl_down(dl, off, 64);
    if (lane == 0) wred[wid] = dl;
    __syncthreads();
    if (tid == 0)
        atomicAdd(sum_sq, wred[0] + wred[1] + wred[2] + wred[3]);
}

// Scan: 256-thread blocks (4 waves); wave = (64-token group, 32-code slice).
// Token-per-lane, wave-uniform cb rows; f64 dot with 4-way ILP + e-unroll-2.
__global__ __launch_bounds__(256) void fixup_scan(
    const float* __restrict__ z, const float* __restrict__ cb,
    const float* __restrict__ c2, const int* __restrict__ wl,
    const int* __restrict__ wl_count, u64* __restrict__ keys) {

    int count = *wl_count; if (count > WLCAP) count = WLCAP;
    const int g = blockIdx.x >> 3;                 // token group (64 tokens)
    if (g * 64 >= count) return;
    const int lane  = threadIdx.x & 63;
    const int slice = (blockIdx.x & 7) * 4 + (threadIdx.x >> 6);  // 32 codes
    const int w = g * 64 + lane;
    const bool valid = w < count;
    const int n = wl[valid ? w : g * 64];

    double zd[E_DIM];
    const float4* zp = (const float4*)(z + (size_t)n * E_DIM);
#pragma unroll
    for (int k = 0; k < 16; ++k) {
        float4 v = zp[k];
        zd[4 * k]     = (double)v.x;
        zd[4 * k + 1] = (double)v.y;
        zd[4 * k + 2] = (double)v.z;
        zd[4 * k + 3] = (double)v.w;
    }
    // numpy-pairwise z2 in f32 (8 accumulators + tree)
    float r8[8];
#pragma unroll
    for (int j = 0; j < 8; ++j) {
        float f = (float)zd[j];
        r8[j] = __fmul_rn(f, f);
    }
#pragma unroll
    for (int i = 8; i < 64; i += 8)
#pragma unroll
        for (int j = 0; j < 8; ++j) {
            float f = (float)zd[i + j];
            r8[j] = __fadd_rn(r8[j], __fmul_rn(f, f));
        }
    const float z2 = __fadd_rn(
        __fadd_rn(__fadd_rn(r8[0], r8[1]), __fadd_rn(r8[2], r8[3])),
        __fadd_rn(__fadd_rn(r8[4], r8[5]), __fadd_rn(r8[6], r8[7])));

    u64 best = ~0ull;
    const int e0 = slice * 32;
#pragma unroll 2
    for (int e = e0; e < e0 + 32; ++e) {
        const float* cp = cb + (size_t)e * E_DIM;   // wave-uniform row
        double m0 = 0.0, m1 = 0.0, m2 = 0.0, m3 = 0.0;
#pragma unroll
        for (int i = 0; i < 16; ++i) {
            m0 = fma(zd[i],      (double)cp[i],      m0);
            m1 = fma(zd[i + 16], (double)cp[i + 16], m1);
            m2 = fma(zd[i + 32], (double)cp[i + 32], m2);
            m3 = fma(zd[i + 48], (double)cp[i + 48], m3);
        }
        float m32 = (float)((m0 + m1) + (m2 + m3));
        float d = __fsub_rn(__fadd_rn(z2, c2[e]), __fmul_rn(2.0f, m32));
        u64 key = ((u64)__float_as_uint(d) << 32) | (unsigned)e;
        if (key < best) best = key;
    }
    if (valid) atomicMin(&keys[w], best);
}

// Apply: one wave per worklist token; finish zq/idx/counts/sum_sq.
__global__ __launch_bounds__(256) void fixup_apply(
    const float* __restrict__ z, const float* __restrict__ cb,
    const int* __restrict__ wl, const int* __restrict__ wl_count,
    const u64* __restrict__ keys, int* __restrict__ counts,
    double* __restrict__ sum_sq, float* __restrict__ out) {

    int count = *wl_count; if (count > WLCAP) count = WLCAP;
    const int lane = threadIdx.x & 63;
    const int gw = blockIdx.x * 4 + (threadIdx.x >> 6);
    for (int w = gw; w < count; w += 1024) {
        const int n = wl[w];
        const int best = (int)(keys[w] & 0xffffffffull);
        float cv = cb[(size_t)best * E_DIM + lane];
        float zi = z[(size_t)n * E_DIM + lane];
        float diff = cv - zi;
        out[ZQ_OFF + (size_t)n * E_DIM + lane] = zi + diff;
        double d2 = (double)diff * (double)diff;
#pragma unroll
        for (int off = 32; off > 0; off >>= 1)
            d2 += __shfl_down(d2, off, 64);
        if (lane == 0) {
            atomicAdd(sum_sq, d2);
            atomicAdd(&counts[best], 1);
            out[IDX_OFF + n] = (float)best;
        }
    }
}

__global__ __launch_bounds__(1024) void finalize_kernel(
    const int* __restrict__ counts, const double* __restrict__ sum_sq,
    float* __restrict__ out) {
    __shared__ double red[1024];
    int e = threadIdx.x;
    double em = (double)counts[e] / (double)N_TOK;
    red[e] = -em * log(em + 1e-10);
    __syncthreads();
    for (int s = 512; s > 0; s >>= 1) {
        if (e < s) red[e] += red[e + s];
        __syncthreads();
    }
    if (e == 0) {
        double usage = red[0];
        double mse = sum_sq[0] / (double)((size_t)N_TOK * E_DIM);
        out[LOSS_OFF] = (float)((1.0 + BETA) * mse + 0.01 * usage);
        out[PERP_OFF] = (float)exp(usage);
    }
}

extern "C" void kernel_launch(void* const* d_in, const int* in_sizes, int n_in,
                              void* d_out, int out_size, void* d_ws, size_t ws_size,
                              hipStream_t stream) {
    const float* z  = (const float*)d_in[0];
    const float* cb = (const float*)d_in[1];
    float* out = (float*)d_out;

    float*  c2     = (float*)((char*)d_ws + WS_C2);
    int*    c2i    = (int*)((char*)d_ws + WS_C2I);
    int*    counts = (int*)((char*)d_ws + WS_CNT);
    double* sum_sq = (double*)((char*)d_ws + WS_SSQ);
    int*    wlc    = (int*)((char*)d_ws + WS_WLC);
    char*   fhi    = (char*)d_ws + WS_FHI;
    char*   flo    = (char*)d_ws + WS_FLO;
    int*    wl     = (int*)((char*)d_ws + WS_WL);
    u64*    keys   = (u64*)((char*)d_ws + WS_KEYS);

    // margin_t = 1e-4 (covers worst-case int8 screen error 4.9e-5 + numpy-f32
    // rounding ~2.5e-5 + slack); margin_v = margin_t * 128/(s_z*s_c) + chop pad
    unsigned margin_v =
        (ws_size >= (size_t)(WS_KEYS + 8 * WLCAP)) ? 26600u : 0u;

    prep_kernel<<<256, 256, 0, stream>>>(cb, c2, c2i, counts, wlc, sum_sq,
                                         fhi, flo, keys);
    vq_main<<<1024, 256, 0, stream>>>(z, cb, c2, c2i, fhi, flo, counts,
                                      sum_sq, wlc, wl, margin_v, out);
    fixup_scan<<<2048, 256, 0, stream>>>(z, cb, c2, wl, wlc, keys);
    fixup_apply<<<256, 256, 0, stream>>>(z, cb, wl, wlc, keys, counts,
                                         sum_sq, out);
    finalize_kernel<<<1, 1024, 0, stream>>>(counts, sum_sq, out);
}

// Round 8
// 296.779 us; speedup vs baseline: 1.0047x; 1.0047x over previous
//
#include <hip/hip_runtime.h>
#include <math.h>

#define N_TOK 131072
#define N_E   1024
#define E_DIM 64
#define BETA  0.4

// d_out layout (float32, concatenated in return order):
#define ZQ_OFF   0
#define LOSS_OFF 8388608
#define IDX_OFF  8388609
#define PERP_OFF 8519681

// d_ws layout (round-2 pass proves ws_size >= 532492; we use 339984):
#define WS_C2    0        // 1024 f32: RN32(exact ||c_e||^2)
#define WS_C2I   4096     // 1024 i32: round(c2 * 128/(s_z*s_c))
#define WS_CNT   8192     // 1024 i32 counts
#define WS_SSQ   12288    // double sum_sq
#define WS_WLC   12296    // int worklist count (+4 pad)
#define WS_FHI   12304    // 65536 B: codebook int8-hi, MFMA B-frag layout
#define WS_FLO   77840    // 65536 B: codebook int8-lo
#define WS_WL    143376   // 16384 ints: worklist
#define WS_KEYS  208912   // 16384 u64: packed (d_bits<<32)|e
#define WLCAP    16384

// fixed-point scales: z = s_z*(zh + zl/256), s_z = 8/127; c = s_c*(ch + cl/256),
// s_c = (1/1024)/127.
#define INV_SZ  15.875f        // 127/8
#define INV_SC  130048.0f      // 127*1024
#define SCALE_D 264257536.0    // 128/(s_z*s_c): c2 -> int units
#define BIGC    0x20000000     // +2^29 offset keeps tracker value positive

typedef int i32x4 __attribute__((ext_vector_type(4)));
typedef unsigned long long u64;

__device__ __forceinline__ void gl2lds16(const void* g, void* l) {
    __builtin_amdgcn_global_load_lds(
        (const __attribute__((address_space(1))) unsigned int*)g,
        (__attribute__((address_space(3))) unsigned int*)l, 16, 0, 0);
}

// One prep kernel: int8 hi/lo B-fragments + c2/c2i + zero-inits.
// Frag element j (0..15) of lane l, chunk c: cb[c*16+(l&15)][(l>>4)*16+j]
// at byte (c*64+l)*16+j.
__global__ __launch_bounds__(256) void prep_kernel(
    const float* __restrict__ cb, float* __restrict__ c2,
    int* __restrict__ c2i, int* __restrict__ counts, int* __restrict__ wlc,
    double* __restrict__ sum_sq, char* __restrict__ fhi,
    char* __restrict__ flo, u64* __restrict__ keys) {
    int tid = blockIdx.x * 256 + threadIdx.x;   // 65536
    int j = tid & 15, l = (tid >> 4) & 63, c = tid >> 10;
    int code = c * 16 + (l & 15);
    int k = ((l >> 4) << 4) | j;
    float cv = cb[code * 64 + k];
    float f = cv * INV_SC;
    float h = rintf(f);
    float lo = rintf((f - h) * 256.f);
    lo = fminf(fmaxf(lo, -127.f), 127.f);
    fhi[tid] = (char)(int)h;
    flo[tid] = (char)(int)lo;
    if (tid < WLCAP) keys[tid] = ~0ull;
    if (tid < N_E) {
        const float* p = cb + tid * 64;
        double s = 0.0;
#pragma unroll
        for (int i = 0; i < 64; ++i) { double d = (double)p[i]; s = fma(d, d, s); }
        c2[tid] = (float)s;
        c2i[tid] = (int)llround(s * SCALE_D);
        counts[tid] = 0;
    }
    if (tid == 0) { *wlc = 0; *sum_sq = 0.0; }
}

// Cold path (worklist overflow only). Exact numpy-f32 semantics, serial.
__device__ __attribute__((noinline)) int exact_best_serial(
    const float* __restrict__ z, const float* __restrict__ cb,
    const float* __restrict__ c2, int n) {
    const float* zr = z + (size_t)n * E_DIM;
    float r[8];
#pragma unroll
    for (int j = 0; j < 8; ++j) r[j] = __fmul_rn(zr[j], zr[j]);
#pragma unroll 1
    for (int i = 8; i < 64; i += 8)
#pragma unroll
        for (int j = 0; j < 8; ++j)
            r[j] = __fadd_rn(r[j], __fmul_rn(zr[i + j], zr[i + j]));
    float z2 = __fadd_rn(__fadd_rn(__fadd_rn(r[0], r[1]), __fadd_rn(r[2], r[3])),
                         __fadd_rn(__fadd_rn(r[4], r[5]), __fadd_rn(r[6], r[7])));
    u64 bestkey = ~0ull;
#pragma unroll 1
    for (int e = 0; e < N_E; ++e) {
        const float* cp = cb + (size_t)e * E_DIM;
        double m = 0.0;
#pragma unroll 1
        for (int i = 0; i < E_DIM; ++i)
            m = fma((double)zr[i], (double)cp[i], m);
        float d = __fsub_rn(__fadd_rn(z2, c2[e]), __fmul_rn(2.0f, (float)m));
        u64 key = ((u64)__float_as_uint(d) << 32) | (unsigned)e;
        if (key < bestkey) bestkey = key;
    }
    return (int)(bestkey & 0xffffffffu);
}

// Screen: 512 blocks x 256 tokens (4 waves, 4 tiles/wave), 2 blocks/CU.
// hi-frags resident in LDS (64 KB, loaded once); lo-frags + c2i read from
// global (L1/L2-hot) each chunk. K-loop has NO barriers.
__global__ __launch_bounds__(256, 2) void vq_main(
    const float* __restrict__ z, const float* __restrict__ cb,
    const float* __restrict__ c2, const int* __restrict__ c2i,
    const char* __restrict__ fhi_, const char* __restrict__ flo_,
    int* __restrict__ counts, double* __restrict__ sum_sq,
    int* __restrict__ wl_count, int* __restrict__ wl,
    unsigned margin_v, float* __restrict__ out) {

    __shared__ char hifrag[65536];   // 64 chunks x 1024 B; aliased post-loop
    int*           best_s = (int*)hifrag;             // [0,1024)
    unsigned char* flag_s = (unsigned char*)hifrag + 1024;  // [1024,1280)
    double*        wred   = (double*)(hifrag + 1280);       // [1280,1312)

    const int tid  = threadIdx.x;
    const int lane = tid & 63;
    const int wid  = tid >> 6;
    const int col  = lane & 15;
    const int quad = lane >> 4;
    const int blk_tok0 = blockIdx.x * 256;
    const int wave_tok0 = blk_tok0 + wid * 64;

    // one-time hi-frag DMA into LDS (identity copy, coalesced)
#pragma unroll
    for (int i = 0; i < 16; ++i)
        gl2lds16(fhi_ + (i * 256 + tid) * 16, hifrag + (i * 256 + tid) * 16);

    // A fragments: 4 tiles, int8 hi/lo, K=64 (overlaps with the DMA above)
    i32x4 Ah[4], Al[4];
#pragma unroll
    for (int m = 0; m < 4; ++m) {
        const float* zr = z + (size_t)(wave_tok0 + m * 16 + col) * E_DIM + quad * 16;
        float e[16];
#pragma unroll
        for (int t = 0; t < 4; ++t) {
            float4 v = *(const float4*)(zr + t * 4);
            e[4 * t] = v.x; e[4 * t + 1] = v.y; e[4 * t + 2] = v.z; e[4 * t + 3] = v.w;
        }
        union { char b[16]; i32x4 v; } ph, pl;
#pragma unroll
        for (int t = 0; t < 16; ++t) {
            float f = e[t] * INV_SZ;
            float h = rintf(f);
            float lo = rintf((f - h) * 256.f);
            lo = fminf(fmaxf(lo, -127.f), 127.f);
            ph.b[t] = (char)(int)h;
            pl.b[t] = (char)(int)lo;
        }
        Ah[m] = ph.v;
        Al[m] = pl.v;
    }

    unsigned k1[4][4], k2[4][4];
#pragma unroll
    for (int m = 0; m < 4; ++m)
#pragma unroll
        for (int r = 0; r < 4; ++r) { k1[m][r] = 0u; k2[m][r] = 0u; }

    __syncthreads();   // hi-frag LDS ready (drains the DMA)

    const i32x4 zeroi = {0, 0, 0, 0};
#pragma unroll 4
    for (int c = 0; c < 64; ++c) {
        i32x4 bh = *(const i32x4*)(hifrag + c * 1024 + lane * 16);
        i32x4 bl = *(const i32x4*)(flo_ + c * 1024 + lane * 16);   // global, L1/L2
        int bias = BIGC - c2i[c * 16 + col];
        i32x4 cinit = {bias, bias, bias, bias};
        const unsigned ctag = (unsigned)(63 - c);
#pragma unroll
        for (int m = 0; m < 4; ++m) {
            i32x4 ahh = __builtin_amdgcn_mfma_i32_16x16x64_i8(Ah[m], bh, zeroi, 0, 0, 0);
            i32x4 amd = __builtin_amdgcn_mfma_i32_16x16x64_i8(Ah[m], bl, cinit, 0, 0, 0);
            amd = __builtin_amdgcn_mfma_i32_16x16x64_i8(Al[m], bh, amd, 0, 0, 0);
#pragma unroll
            for (int r = 0; r < 4; ++r) {
                unsigned v = ((unsigned)ahh[r] << 8) + (unsigned)amd[r];
                unsigned key = (v & 0xFFFFFFC0u) | ctag;
                unsigned lo2 = min(k1[m][r], key);
                k2[m][r] = max(k2[m][r], lo2);
                k1[m][r] = max(k1[m][r], key);
            }
        }
    }

    __syncthreads();   // all LDS frag reads done -> safe to alias best_s/flag_s

    // merge + decide, per (m,r): maximize key; ties -> lower chunk (ctag order),
    // then lower col.
#pragma unroll
    for (int m = 0; m < 4; ++m) {
#pragma unroll
        for (int r = 0; r < 4; ++r) {
            unsigned ku1 = k1[m][r], ku2 = k2[m][r];
            int b1 = (63 - (int)(ku1 & 63u)) * 16 + col;
#pragma unroll
            for (int d = 1; d < 16; d <<= 1) {
                unsigned o1 = (unsigned)__shfl_xor((int)ku1, d, 64);
                unsigned o2 = (unsigned)__shfl_xor((int)ku2, d, 64);
                int      ob = __shfl_xor(b1, d, 64);
                unsigned n2 = max(max(ku2, o2), min(ku1, o1));
                bool take = (o1 > ku1) || (o1 == ku1 && ob < b1);
                ku1 = max(ku1, o1);
                b1 = take ? ob : b1;
                ku2 = n2;
            }
            if (col == 0) {
                int tl = wid * 64 + m * 16 + quad * 4 + r;
                int n  = blk_tok0 + tl;
                int best = b1;
                bool fl = (ku1 - ku2) < margin_v;
                if (fl) {
                    int pos = atomicAdd(wl_count, 1);
                    if (pos < WLCAP) wl[pos] = n;
                    else { best = exact_best_serial(z, cb, c2, n); fl = false; }
                }
                best_s[tl] = best;
                flag_s[tl] = fl ? 1 : 0;
                if (!fl) atomicAdd(&counts[best], 1);
            }
        }
    }
    __syncthreads();

    // coalesced idx write (flagged slots overwritten by fixup_apply)
    out[IDX_OFF + blk_tok0 + tid] = (float)best_s[tid];

    // epilogue: coalesced z_q / loss for unflagged tokens
    const int sub = tid & 15, grp = tid >> 4;
    double dl = 0.0;
    const float4* zrow = (const float4*)z;
    const float4* crow = (const float4*)cb;
    float4* qrow = (float4*)(out + ZQ_OFF);
#pragma unroll
    for (int p = 0; p < 16; ++p) {
        int tl = p * 16 + grp;
        if (!flag_s[tl]) {
            int n = blk_tok0 + tl;
            float4 z4 = zrow[(size_t)n * 16 + sub];
            float4 c4 = crow[(size_t)best_s[tl] * 16 + sub];
            float dx = c4.x - z4.x, dy = c4.y - z4.y;
            float dz = c4.z - z4.z, dw = c4.w - z4.w;
            float4 q;
            q.x = z4.x + dx; q.y = z4.y + dy;
            q.z = z4.z + dz; q.w = z4.w + dw;
            qrow[(size_t)n * 16 + sub] = q;
            dl += (double)dx * dx + (double)dy * dy
                + (double)dz * dz + (double)dw * dw;
        }
    }
#pragma unroll
    for (int off = 32; off > 0; off >>= 1)
        dl += __shfl_down(dl, off, 64);
    if (lane == 0) wred[wid] = dl;
    __syncthreads();
    if (tid == 0)
        atomicAdd(sum_sq, wred[0] + wred[1] + wred[2] + wred[3]);
}

// Scan: block = 4 waves sharing one 64-token group; waves cover 4 of the
// group's 32 code-slices. Token rows staged ONCE per block into padded LDS
// (coalesced); cb rows wave-uniform; f64 dot 4 chains + unroll 2.
__global__ __launch_bounds__(256) void fixup_scan(
    const float* __restrict__ z, const float* __restrict__ cb,
    const float* __restrict__ c2, const int* __restrict__ wl,
    const int* __restrict__ wl_count, u64* __restrict__ keys) {

    __shared__ float zs[64][65];   // +1 pad: conflict-free column reads

    int count = *wl_count; if (count > WLCAP) count = WLCAP;
    const int g = blockIdx.x >> 3;
    if (g * 64 >= count) return;
    const int tid = threadIdx.x;
    const int lane = tid & 63;
    const int slice = (blockIdx.x & 7) * 4 + (tid >> 6);   // 0..31

    // stage: thread t loads 16 consecutive floats of row t/4 (coalesced per row)
    {
        int row = tid >> 2, c0 = (tid & 3) * 16;
        int w = g * 64 + row;
        int n = wl[w < count ? w : g * 64];
        const float* src = z + (size_t)n * E_DIM + c0;
#pragma unroll
        for (int i = 0; i < 16; ++i) zs[row][c0 + i] = src[i];
    }
    __syncthreads();

    // lane's token row -> f64 regs + numpy-pairwise z2 (f32, 8 acc + tree)
    double zd[E_DIM];
    float r8[8];
#pragma unroll
    for (int j = 0; j < 8; ++j) {
        float f = zs[lane][j];
        zd[j] = (double)f;
        r8[j] = __fmul_rn(f, f);
    }
#pragma unroll
    for (int i = 8; i < 64; i += 8)
#pragma unroll
        for (int j = 0; j < 8; ++j) {
            float f = zs[lane][i + j];
            zd[i + j] = (double)f;
            r8[j] = __fadd_rn(r8[j], __fmul_rn(f, f));
        }
    const float z2 = __fadd_rn(
        __fadd_rn(__fadd_rn(r8[0], r8[1]), __fadd_rn(r8[2], r8[3])),
        __fadd_rn(__fadd_rn(r8[4], r8[5]), __fadd_rn(r8[6], r8[7])));

    u64 best = ~0ull;
    const int e0 = slice * 32;
#pragma unroll 2
    for (int e = e0; e < e0 + 32; ++e) {
        const float* cp = cb + (size_t)e * E_DIM;   // wave-uniform row
        double m0 = 0.0, m1 = 0.0, m2 = 0.0, m3 = 0.0;
#pragma unroll
        for (int i = 0; i < 16; ++i) {
            m0 = fma(zd[i],      (double)cp[i],      m0);
            m1 = fma(zd[i + 16], (double)cp[i + 16], m1);
            m2 = fma(zd[i + 32], (double)cp[i + 32], m2);
            m3 = fma(zd[i + 48], (double)cp[i + 48], m3);
        }
        float m32 = (float)((m0 + m1) + (m2 + m3));
        float d = __fsub_rn(__fadd_rn(z2, c2[e]), __fmul_rn(2.0f, m32));
        u64 key = ((u64)__float_as_uint(d) << 32) | (unsigned)e;
        if (key < best) best = key;
    }
    if (g * 64 + lane < count) atomicMin(&keys[g * 64 + lane], best);
}

// Apply: one wave per worklist token; finish zq/idx/counts/sum_sq.
__global__ __launch_bounds__(256) void fixup_apply(
    const float* __restrict__ z, const float* __restrict__ cb,
    const int* __restrict__ wl, const int* __restrict__ wl_count,
    const u64* __restrict__ keys, int* __restrict__ counts,
    double* __restrict__ sum_sq, float* __restrict__ out) {

    int count = *wl_count; if (count > WLCAP) count = WLCAP;
    const int lane = threadIdx.x & 63;
    const int gw = blockIdx.x * 4 + (threadIdx.x >> 6);
    for (int w = gw; w < count; w += 1024) {
        const int n = wl[w];
        const int best = (int)(keys[w] & 0xffffffffull);
        float cv = cb[(size_t)best * E_DIM + lane];
        float zi = z[(size_t)n * E_DIM + lane];
        float diff = cv - zi;
        out[ZQ_OFF + (size_t)n * E_DIM + lane] = zi + diff;
        double d2 = (double)diff * (double)diff;
#pragma unroll
        for (int off = 32; off > 0; off >>= 1)
            d2 += __shfl_down(d2, off, 64);
        if (lane == 0) {
            atomicAdd(sum_sq, d2);
            atomicAdd(&counts[best], 1);
            out[IDX_OFF + n] = (float)best;
        }
    }
}

__global__ __launch_bounds__(1024) void finalize_kernel(
    const int* __restrict__ counts, const double* __restrict__ sum_sq,
    float* __restrict__ out) {
    __shared__ double red[1024];
    int e = threadIdx.x;
    double em = (double)counts[e] / (double)N_TOK;
    red[e] = -em * log(em + 1e-10);
    __syncthreads();
    for (int s = 512; s > 0; s >>= 1) {
        if (e < s) red[e] += red[e + s];
        __syncthreads();
    }
    if (e == 0) {
        double usage = red[0];
        double mse = sum_sq[0] / (double)((size_t)N_TOK * E_DIM);
        out[LOSS_OFF] = (float)((1.0 + BETA) * mse + 0.01 * usage);
        out[PERP_OFF] = (float)exp(usage);
    }
}

extern "C" void kernel_launch(void* const* d_in, const int* in_sizes, int n_in,
                              void* d_out, int out_size, void* d_ws, size_t ws_size,
                              hipStream_t stream) {
    const float* z  = (const float*)d_in[0];
    const float* cb = (const float*)d_in[1];
    float* out = (float*)d_out;

    float*  c2     = (float*)((char*)d_ws + WS_C2);
    int*    c2i    = (int*)((char*)d_ws + WS_C2I);
    int*    counts = (int*)((char*)d_ws + WS_CNT);
    double* sum_sq = (double*)((char*)d_ws + WS_SSQ);
    int*    wlc    = (int*)((char*)d_ws + WS_WLC);
    char*   fhi    = (char*)d_ws + WS_FHI;
    char*   flo    = (char*)d_ws + WS_FLO;
    int*    wl     = (int*)((char*)d_ws + WS_WL);
    u64*    keys   = (u64*)((char*)d_ws + WS_KEYS);

    unsigned margin_v =
        (ws_size >= (size_t)(WS_KEYS + 8 * WLCAP)) ? 26600u : 0u;

    prep_kernel<<<256, 256, 0, stream>>>(cb, c2, c2i, counts, wlc, sum_sq,
                                         fhi, flo, keys);
    vq_main<<<512, 256, 0, stream>>>(z, cb, c2, c2i, fhi, flo, counts,
                                     sum_sq, wlc, wl, margin_v, out);
    fixup_scan<<<2048, 256, 0, stream>>>(z, cb, c2, wl, wlc, keys);
    fixup_apply<<<256, 256, 0, stream>>>(z, cb, wl, wlc, keys, counts,
                                         sum_sq, out);
    finalize_kernel<<<1, 1024, 0, stream>>>(counts, sum_sq, out);
}